// Round 25
// baseline (47.518 us; speedup 1.0000x reference)
//
#include <hip/hip_runtime.h>

#define HID 64
#define NTOK 66           // VOCAB_SIZE + 2
#define SEQ 64
#define WIN0 55           // SEQ_LEN - 1 - MEMORY_SLOTS
#define NW 8
#define LDS_STRIDE 72     // ushorts per table/h row (144B)
#define ITERS 16          // iterations per block (rows/block = 2048, grid = 256)
#define BLOCK 512         // 8 waves: 0-3 producers, 4-7 consumers
#define ROWS_PER_ITER 128 // 8 tiles x 16 rows
#define HOFF (2 * NTOK * LDS_STRIDE)       // ushort offset of h region
#define HBUF (ROWS_PER_ITER * LDS_STRIDE)  // one h buffer (9216 ushorts)

typedef _Float16 half8 __attribute__((ext_vector_type(8)));
typedef unsigned short ushort8v __attribute__((ext_vector_type(8)));
typedef float float4v __attribute__((ext_vector_type(4)));

static __device__ __forceinline__ unsigned short f2h(float f) {
    _Float16 h = (_Float16)f;
    union { _Float16 h; unsigned short u; } v; v.h = h;
    return v.u;
}

// Kernel 1: tables T1[t][n] = b1[n] + sum_k emb[t][k]*W1[n][k]
//           T2[t][n] = 0.125 * sum_k emb[t][k]*W1[n][64+k]   (f16)
__global__ void build_tables(const float* __restrict__ embed,
                             const float* __restrict__ W1,
                             const float* __restrict__ b1,
                             unsigned short* __restrict__ tbl) {
    int b = blockIdx.x;      // 0..131
    int tb = b & 1;
    int t  = b >> 1;
    int n  = threadIdx.x;    // 0..63
    float acc = tb ? 0.0f : b1[n];
    const float* er = embed + t * HID;
    const float* wr = W1 + n * (2 * HID) + tb * HID;
#pragma unroll 8
    for (int k = 0; k < HID; ++k) acc += er[k] * wr[k];
    if (tb) acc *= 0.125f;
    tbl[tb * (NTOK * HID) + t * HID + n] = f2h(acc);
}

// Kernel 2: P/C WAVE SPECIALIZATION + HALVED BARRIER CADENCE (4-buf ring).
// R21 (best, 44.8us): 2 h-buffers, barrier/iter -> 16 syncs; consumer
// (~1K cy work) idles at every barrier against the producer's ~5-6K chain,
// and both roles restart their memory pipelines 16 times. This version:
// 4 h-buffers, barrier every 2 iterations -> producers run TWO independent
// PRODUCE bodies back-to-back (72 ds_reads of natural dual-chain MLP --
// R16's ILP form, which the compiler pipelines well WITHOUT forced-wide
// windows: R24's sched_barrier forcing regressed), consumers drain two
// buffers per round, half the syncs. Ring safety: buf b written round r,
// read r+1, rewritten r+2 -- a full barrier between every write/read.
// Token slots cycle mod 4, all indices compile-time (static registers).
// Falsified levers (do not revisit): nontemporal (R10), global gather
// (R13/R20), s_sleep stagger (R14), zero-load loop (R17), bank-uniform
// gather (R18), 2 blocks/CU P/C (R22), lgkm-only barrier (R23 null),
// forced-wide read window (R24).
__global__ __launch_bounds__(BLOCK, 2) void fused_forward(
    const int* __restrict__ seqs,
    const int* __restrict__ qtok,
    const float* __restrict__ W2,
    const float* __restrict__ b2,
    const unsigned short* __restrict__ tbl,
    float* __restrict__ out)
{
    // tables 19008 B + 4 h-buffers x 18432 B = 92736 B
    __shared__ unsigned short T_lds[HOFF + 4 * HBUF];

    int tid  = threadIdx.x;
    int wv   = tid >> 6;        // 0..7
    int l    = tid & 63;
    int lrow = l & 15;          // row within tile / W2 row within n-tile
    int lg   = l >> 4;          // k-chunk quarter / output col group
    int lk8  = lg * 8;          // k offset within 32-wide K chunk (ushorts)
    int tile0 = wv & 3;         // this wave's tiles: tile0 and tile0+4

    int blk0 = blockIdx.x * (ITERS * ROWS_PER_ITER);
    // producer token rows for its 2 tiles (iter t adds t*128)
    int prow0 = blk0 + tile0 * 16 + lrow;
    int prow1 = prow0 + 64;

    // token slots (mod-4 ring, all statically indexed)
    int qS0, qS1, qS2, qS3;
    int wS0[NW], wS1[NW], wS2[NW], wS3[NW];

// producer token loads for iter t_ into slot S (S = t_ & 3)
#define LOADT(S, t_) { \
    int r0_ = prow0 + (t_) * ROWS_PER_ITER; \
    int r1_ = prow1 + (t_) * ROWS_PER_ITER; \
    qS##S = qtok[r0_]; \
    /* second tile's query token shares slot: pack into wS via extra reg */ \
    q2S##S = qtok[r1_]; \
    const int* s0_ = seqs + r0_ * SEQ + WIN0; \
    const int* s1_ = seqs + r1_ * SEQ + WIN0; \
    _Pragma("unroll") \
    for (int j = 0; j < NW; ++j) { wS##S[j] = s0_[j]; w2S##S[j] = s1_[j]; } \
}
    int q2S0, q2S1, q2S2, q2S3;
    int w2S0[NW], w2S1[NW], w2S2[NW], w2S3[NW];

#define RD_T1(qq, koff) (*(const half8*)(T_lds + (qq) * LDS_STRIDE + (koff)))
#define RD_T2(ww, koff) (*(const half8*)(T_lds + NTOK * LDS_STRIDE + (ww) * LDS_STRIDE + (koff)))

// producer: gather+sum+relu both tiles from slot S, write to buf_ (== S)
#define PRODUCE(S, buf_) { \
    unsigned short* hb_ = T_lds + HOFF + (buf_) * HBUF; \
    half8 s0_ = RD_T1(qS##S, lk8); \
    half8 s1_ = RD_T1(qS##S, 32 + lk8); \
    half8 u0_ = RD_T1(q2S##S, lk8); \
    half8 u1_ = RD_T1(q2S##S, 32 + lk8); \
    _Pragma("unroll") \
    for (int j = 0; j < NW; ++j) { \
        s0_ += RD_T2(wS##S[j], lk8); \
        s1_ += RD_T2(wS##S[j], 32 + lk8); \
        u0_ += RD_T2(w2S##S[j], lk8); \
        u1_ += RD_T2(w2S##S[j], 32 + lk8); \
    } \
    half8 z_ = (half8)(_Float16)0; \
    s0_ = __builtin_elementwise_max(s0_, z_); \
    s1_ = __builtin_elementwise_max(s1_, z_); \
    u0_ = __builtin_elementwise_max(u0_, z_); \
    u1_ = __builtin_elementwise_max(u1_, z_); \
    unsigned short* r0_ = hb_ + (tile0 * 16 + lrow) * LDS_STRIDE; \
    unsigned short* r1_ = hb_ + ((tile0 + 4) * 16 + lrow) * LDS_STRIDE; \
    *(half8*)(r0_ + lk8) = s0_; \
    *(half8*)(r0_ + 32 + lk8) = s1_; \
    *(half8*)(r1_ + lk8) = u0_; \
    *(half8*)(r1_ + 32 + lk8) = u1_; \
}

// consumer: read h fragments for both tiles from buf_, MFMA, store
#define CONSUME(t_, buf_) { \
    const unsigned short* hb_ = T_lds + HOFF + (buf_) * HBUF; \
    _Pragma("unroll") \
    for (int pt = 0; pt < 2; ++pt) { \
        int trow_ = (tile0 + pt * 4) * 16 + lrow; \
        half8 a0_ = *(const half8*)(hb_ + trow_ * LDS_STRIDE + lk8); \
        half8 a1_ = *(const half8*)(hb_ + trow_ * LDS_STRIDE + 32 + lk8); \
        float* op_ = out + (size_t)(blk0 + (t_) * ROWS_PER_ITER + trow_) * HID; \
        _Pragma("unroll") \
        for (int nt = 0; nt < 4; ++nt) { \
            float4v acc_ = __builtin_amdgcn_mfma_f32_16x16x32_f16(wfrag[nt][0], a0_, b2v[nt], 0, 0, 0); \
            acc_ = __builtin_amdgcn_mfma_f32_16x16x32_f16(wfrag[nt][1], a1_, acc_, 0, 0, 0); \
            *(float4v*)(op_ + nt * 16 + lg * 4) = acc_; \
        } \
    } \
}

// one round = 2 iterations, ONE barrier.
// consumers drain iters i0,i1 (bufs i0&3,i1&3); producers fill iters
// i0+2,i1+2 (bufs (i0+2)&3,(i1+2)&3) and prefetch tokens for i0+4,i1+4.
#define ROUND(i0, i1, l0, l1, doload) { \
    if (wv >= 4) { CONSUME(i0, (i0) & 3); CONSUME(i1, (i1) & 3); } \
    else { \
        PRODUCE(((i0 + 2) & 3), ((i0 + 2) & 3)); \
        PRODUCE(((i1 + 2) & 3), ((i1 + 2) & 3)); \
        if (doload) { LOADT(((l0) & 3), l0); LOADT(((l1) & 3), l1); } \
    } \
    __syncthreads(); \
}
// NOTE: macro token-pasting needs literal slot digits; write rounds manually.

    // ---- (1) producers: tokens for iters 0..3; consumers: W2 frags ----
    half8   wfrag[4][2];
    float4v b2v[4];
    if (wv < 4) {
        LOADT(0, 0);
        LOADT(1, 1);
        LOADT(2, 2);
        LOADT(3, 3);
    } else {
#pragma unroll
        for (int nt = 0; nt < 4; ++nt) {
            b2v[nt] = *(const float4v*)(b2 + nt * 16 + lg * 4);
#pragma unroll
            for (int kc = 0; kc < 2; ++kc) {
                const float* wp = W2 + (nt * 16 + lrow) * HID + kc * 32 + lk8;
                half8 f;
#pragma unroll
                for (int j = 0; j < 8; ++j) f[j] = (_Float16)wp[j];
                wfrag[nt][kc] = f;
            }
        }
    }

    // ---- (2) all waves: fill LDS tables (16B chunks; row stride 144B) ----
    for (int i = tid; i < 2 * NTOK * (HID / 8); i += BLOCK) {
        int tbi = i / (NTOK * 8);
        int rem = i - tbi * (NTOK * 8);
        int t   = rem >> 3;
        int kq  = (rem & 7) << 3;
        *(ushort8v*)(T_lds + tbi * (NTOK * LDS_STRIDE) + t * LDS_STRIDE + kq) =
            *(const ushort8v*)(tbl + tbi * (NTOK * HID) + t * HID + kq);
    }
    __syncthreads();

    // ---- (3) prologue: producers fill buf0/buf1 with iters 0,1 ----
    if (wv < 4) {
        PRODUCE(0, 0);
        PRODUCE(1, 1);
    }
    __syncthreads();

    // ---- (4) 8 rounds of {consume 2 iters || produce 2 iters}, 1 barrier each ----
    // round 0: consume 0,1 | produce 2,3 | load 4,5
    if (wv >= 4) { CONSUME(0, 0); CONSUME(1, 1); }
    else { PRODUCE(2, 2); PRODUCE(3, 3); LOADT(0, 4); LOADT(1, 5); }
    __syncthreads();
    // round 1: consume 2,3 | produce 4,5 | load 6,7
    if (wv >= 4) { CONSUME(2, 2); CONSUME(3, 3); }
    else { PRODUCE(0, 0); PRODUCE(1, 1); LOADT(2, 6); LOADT(3, 7); }
    __syncthreads();
    // round 2: consume 4,5 | produce 6,7 | load 8,9
    if (wv >= 4) { CONSUME(4, 0); CONSUME(5, 1); }
    else { PRODUCE(2, 2); PRODUCE(3, 3); LOADT(0, 8); LOADT(1, 9); }
    __syncthreads();
    // round 3: consume 6,7 | produce 8,9 | load 10,11
    if (wv >= 4) { CONSUME(6, 2); CONSUME(7, 3); }
    else { PRODUCE(0, 0); PRODUCE(1, 1); LOADT(2, 10); LOADT(3, 11); }
    __syncthreads();
    // round 4: consume 8,9 | produce 10,11 | load 12,13
    if (wv >= 4) { CONSUME(8, 0); CONSUME(9, 1); }
    else { PRODUCE(2, 2); PRODUCE(3, 3); LOADT(0, 12); LOADT(1, 13); }
    __syncthreads();
    // round 5: consume 10,11 | produce 12,13 | load 14,15
    if (wv >= 4) { CONSUME(10, 2); CONSUME(11, 3); }
    else { PRODUCE(0, 0); PRODUCE(1, 1); LOADT(2, 14); LOADT(3, 15); }
    __syncthreads();
    // round 6: consume 12,13 | produce 14,15
    if (wv >= 4) { CONSUME(12, 0); CONSUME(13, 1); }
    else { PRODUCE(2, 2); PRODUCE(3, 3); }
    __syncthreads();
    // round 7: consume 14,15
    if (wv >= 4) { CONSUME(14, 2); CONSUME(15, 3); }

#undef LOADT
#undef RD_T1
#undef RD_T2
#undef PRODUCE
#undef CONSUME
#undef ROUND
}

extern "C" void kernel_launch(void* const* d_in, const int* in_sizes, int n_in,
                              void* d_out, int out_size, void* d_ws, size_t ws_size,
                              hipStream_t stream) {
    const int*   seqs  = (const int*)d_in[0];
    const int*   qtok  = (const int*)d_in[1];
    const float* embed = (const float*)d_in[2];
    const float* W1    = (const float*)d_in[3];
    const float* b1    = (const float*)d_in[4];
    const float* W2    = (const float*)d_in[5];
    const float* b2    = (const float*)d_in[6];
    float* out = (float*)d_out;
    unsigned short* tbl = (unsigned short*)d_ws;

    int B = in_sizes[0] / SEQ;

    build_tables<<<NTOK * 2, HID, 0, stream>>>(embed, W1, b1, tbl);

    int grid = B / (ITERS * ROWS_PER_ITER);
    fused_forward<<<grid, BLOCK, 0, stream>>>(seqs, qtok, W2, b2, tbl, out);
}